// Round 7
// baseline (735.635 us; speedup 1.0000x reference)
//
#include <hip/hip_runtime.h>
#include <math.h>

// NeuralTPP: B=4096, L=512, H=HH=32 — MFMA + batched-ILP formulation.
// One wave per block, 16 sequences per wave, 256 blocks (1 wave/CU).
// Per step: C[128,16] = W[128,32] x H[32,16] as 8x mfma_f32_16x16x32_f16,
// with the row permutation (verified R5, absmax 0) that makes each lane's
// C registers exactly its next-step B-fragment k-slots (zero repack).
// Gate math restructured into 8-wide PHASE ARRAYS so the 8 per-unit
// sigmoid/tanh chains interleave (ILP) instead of serializing on one
// in-order wave. Intensity (tanh+reduce+store) is software-pipelined
// into the next step's MFMA shadow. Phase 2 (softplus/log) unchanged.

constexpr int Bn = 4096;
constexpr int Ln = 512;
constexpr float EPSf = 1e-8f;

typedef _Float16 f16x8 __attribute__((ext_vector_type(8)));
typedef float    f32x4 __attribute__((ext_vector_type(4)));

__device__ __forceinline__ float sigmoidf_(float x) {
    return __fdividef(1.0f, 1.0f + __expf(-x));
}
__device__ __forceinline__ float softplusf_(float x) {
    return fmaxf(x, 0.0f) + __logf(1.0f + __expf(-fabsf(x)));
}

union PK2 { _Float16 f[2]; unsigned u; };

__global__ __launch_bounds__(64, 1)
void tpp_main(const float* __restrict__ deltas,
              const float* __restrict__ mask,
              const float* __restrict__ w_ih,
              const float* __restrict__ w_hh,
              const float* __restrict__ b_ih,
              const float* __restrict__ b_hh,
              const float* __restrict__ w1,
              const float* __restrict__ b1,
              const float* __restrict__ w2,
              const float* __restrict__ b2,
              float* __restrict__ partials)   // [2 * gridDim.x]
{
    const int l  = threadIdx.x;          // 0..63
    const int c  = l & 15;               // batch column
    const int g  = l >> 4;               // 0..3 (k-group / row-group)
    const int b0 = blockIdx.x * 16;

    __shared__ unsigned buf[16][Ln];     // fp16-packed (raw, v2s) = 32 KiB

    // ---- A fragments: 8 tiles (r0,r1,z0,z1,n0,n1,p0,p1), fp16, registers ----
    f16x8 Af[8];
    {
        const int rr = c;
        const int j0 = 8 * g;
#pragma unroll
        for (int T = 0; T < 8; ++T) {
            const int G = T >> 1, p = T & 1;
            const int u = 8 * (rr >> 2) + 4 * p + (rr & 3);
            const float* src =
                (G == 0) ? (w_hh + (size_t)u * 32 + j0) :
                (G == 1) ? (w_hh + (size_t)(32 + u) * 32 + j0) :
                (G == 2) ? (w_hh + (size_t)(64 + u) * 32 + j0) :
                           (w1   + (size_t)u * 33 + 1 + j0);
#pragma unroll
            for (int e = 0; e < 8; ++e) Af[T][e] = (_Float16)src[e];
        }
    }

    // ---- per-unit scalars for this lane's 8 units u = 8g + e ----
    float wihr[8], wihz[8], wihn[8], br[8], bz[8], bin[8], bhn[8];
    float w1t[8], b1v[8], w2v[8], civ[8];
    float civs = 0.0f;
#pragma unroll
    for (int e = 0; e < 8; ++e) {
        const int u = 8 * g + e;
        wihr[e] = w_ih[u];
        wihz[e] = w_ih[32 + u];
        wihn[e] = w_ih[64 + u];
        br[e]   = b_ih[u]      + b_hh[u];
        bz[e]   = b_ih[32 + u] + b_hh[32 + u];
        bin[e]  = b_ih[64 + u];
        bhn[e]  = b_hh[64 + u];
        w1t[e]  = w1[(size_t)u * 33];
        b1v[e]  = b1[u];
        w2v[e]  = w2[u];
        civ[e]  = w1t[e] * w2v[e];
        civs   += civ[e];
    }
    const float b2v = b2[0];

    const float* dp0 = deltas + (size_t)(b0 + c) * Ln;
    const float* mp0 = mask   + (size_t)(b0 + c) * Ln;

    float hreg[8];
#pragma unroll
    for (int e = 0; e < 8; ++e) hreg[e] = 0.0f;

    float tau = dp0[0];
    float m   = mp0[0];

    const f32x4 z4 = {0.0f, 0.0f, 0.0f, 0.0f};

    float ppx[8];                         // intensity pre-acts of step t-1

    for (int t = 0; t < Ln; ++t) {
        const int tn = (t + 1 < Ln) ? (t + 1) : (Ln - 1);
        const float tau_n = dp0[tn];
        const float m_n   = mp0[tn];

        // ---- B fragment + 8 MFMAs (issued first; results awaited later) ----
        f16x8 bf;
#pragma unroll
        for (int e = 0; e < 8; ++e) bf[e] = (_Float16)hreg[e];
        f32x4 acc[8];
#pragma unroll
        for (int T = 0; T < 8; ++T)
            acc[T] = __builtin_amdgcn_mfma_f32_16x16x32_f16(Af[T], bf, z4, 0, 0, 0);

        // ---- deferred intensity of step t-1 (fills the MFMA shadow) ----
        if (t > 0) {
            float aex[8];
#pragma unroll
            for (int e = 0; e < 8; ++e)
                aex[e] = __expf(2.0f * fminf(ppx[e], 15.0f));
            float v1p = 0.0f, v2p = civs;
#pragma unroll
            for (int e = 0; e < 8; ++e) {
                const float a = __fdividef(aex[e] - 1.0f, aex[e] + 1.0f);
                v1p = fmaf(a, w2v[e], v1p);
                v2p = fmaf(a * a, -civ[e], v2p);
            }
            v1p += __shfl_xor(v1p, 16, 64);
            v1p += __shfl_xor(v1p, 32, 64);
            v2p += __shfl_xor(v2p, 16, 64);
            v2p += __shfl_xor(v2p, 32, 64);
            if (l < 16) {
                PK2 pk;
                pk.f[0] = (_Float16)(v1p + b2v);
                pk.f[1] = (_Float16)v2p;
                buf[l][t - 1] = pk.u;
            }
        }

        // ---- gates, 8-wide phase arrays (forces ILP across units) ----
        float rpe[8], zpe[8];
#pragma unroll
        for (int e = 0; e < 8; ++e) {
            rpe[e] = acc[(e >> 2)][e & 3]     + fmaf(tau, wihr[e], br[e]);
            zpe[e] = acc[2 + (e >> 2)][e & 3] + fmaf(tau, wihz[e], bz[e]);
        }
        float rex[8], zex[8];
#pragma unroll
        for (int e = 0; e < 8; ++e) rex[e] = __expf(-rpe[e]);
#pragma unroll
        for (int e = 0; e < 8; ++e) zex[e] = __expf(-zpe[e]);
        float rg[8], zg[8];
#pragma unroll
        for (int e = 0; e < 8; ++e) rg[e] = __frcp_rn(1.0f + rex[e]);
#pragma unroll
        for (int e = 0; e < 8; ++e) zg[e] = __frcp_rn(1.0f + zex[e]);

        float npe[8];
#pragma unroll
        for (int e = 0; e < 8; ++e) {
            const float gn = acc[4 + (e >> 2)][e & 3] + bhn[e];
            npe[e] = fmaf(tau, wihn[e], bin[e]) + rg[e] * gn;
            ppx[e] = acc[6 + (e >> 2)][e & 3] + fmaf(tau, w1t[e], b1v[e]);
        }
        float nex[8];
#pragma unroll
        for (int e = 0; e < 8; ++e)
            nex[e] = __expf(2.0f * fminf(npe[e], 15.0f));
#pragma unroll
        for (int e = 0; e < 8; ++e) {
            const float nn = __fdividef(nex[e] - 1.0f, nex[e] + 1.0f);
            const float hn2 = fmaf(zg[e], hreg[e] - nn, nn);
            hreg[e] = fmaf(m, hn2 - hreg[e], hreg[e]);
        }

        tau = tau_n;
        m   = m_n;
    }

    // ---- tail: intensity for t = Ln-1 ----
    {
        float aex[8];
#pragma unroll
        for (int e = 0; e < 8; ++e)
            aex[e] = __expf(2.0f * fminf(ppx[e], 15.0f));
        float v1p = 0.0f, v2p = civs;
#pragma unroll
        for (int e = 0; e < 8; ++e) {
            const float a = __fdividef(aex[e] - 1.0f, aex[e] + 1.0f);
            v1p = fmaf(a, w2v[e], v1p);
            v2p = fmaf(a * a, -civ[e], v2p);
        }
        v1p += __shfl_xor(v1p, 16, 64);
        v1p += __shfl_xor(v1p, 32, 64);
        v2p += __shfl_xor(v2p, 16, 64);
        v2p += __shfl_xor(v2p, 32, 64);
        if (l < 16) {
            PK2 pk;
            pk.f[0] = (_Float16)(v1p + b2v);
            pk.f[1] = (_Float16)v2p;
            buf[l][Ln - 1] = pk.u;
        }
    }

    __syncthreads();

    // ---- phase 2: LL transcendentals over 16 x 512 items ----
    float T = 0.0f, M = 0.0f;
    for (int it = 0; it < 128; ++it) {
        const int idx = it * 64 + l;        // c*512 + t
        const int cc  = idx >> 9;
        const int tt  = idx & 511;
        PK2 pk; pk.u = buf[cc][tt];
        const float raw = (float)pk.f[0];
        const float v2  = (float)pk.f[1];
        const float mm  = mask[(size_t)(b0 + cc) * Ln + tt];
        const float phi  = softplusf_(raw);
        const float dphi = sigmoidf_(raw) * v2;
        const float lam  = softplusf_(dphi) + EPSf;
        T = fmaf(__logf(lam) - phi, mm, T);
        M += mm;
    }
#pragma unroll
    for (int d = 1; d < 64; d <<= 1) {
        T += __shfl_xor(T, d, 64);
        M += __shfl_xor(M, d, 64);
    }
    if (l == 0) {
        partials[blockIdx.x]             = T;
        partials[gridDim.x + blockIdx.x] = M;
    }
}

__global__ __launch_bounds__(256)
void tpp_final(const float* __restrict__ partials, int nparts,
               float* __restrict__ out)
{
    const int tid = threadIdx.x;
    double T = 0.0, M = 0.0;
    for (int k = tid; k < nparts; k += 256) {
        T += (double)partials[k];
        M += (double)partials[nparts + k];
    }
#pragma unroll
    for (int d = 1; d < 64; d <<= 1) {
        T += __shfl_xor(T, d, 64);
        M += __shfl_xor(M, d, 64);
    }
    __shared__ double sT[4], sM[4];
    const int w = tid >> 6;
    if ((tid & 63) == 0) { sT[w] = T; sM[w] = M; }
    __syncthreads();
    if (tid == 0) {
        const double t2 = sT[0] + sT[1] + sT[2] + sT[3];
        const double m2 = sM[0] + sM[1] + sM[2] + sM[3];
        out[0] = (float)(t2 / (m2 + (double)EPSf));
    }
}

extern "C" void kernel_launch(void* const* d_in, const int* in_sizes, int n_in,
                              void* d_out, int out_size, void* d_ws, size_t ws_size,
                              hipStream_t stream) {
    const float* deltas = (const float*)d_in[0];
    const float* mask   = (const float*)d_in[1];
    const float* w_ih   = (const float*)d_in[2];
    const float* w_hh   = (const float*)d_in[3];
    const float* b_ih   = (const float*)d_in[4];
    const float* b_hh   = (const float*)d_in[5];
    const float* w1     = (const float*)d_in[6];
    const float* b1     = (const float*)d_in[7];
    const float* w2     = (const float*)d_in[8];
    const float* b2     = (const float*)d_in[9];
    float* out = (float*)d_out;
    float* partials = (float*)d_ws;      // 2 * 256 * 4 B

    const int nblocks = Bn / 16;         // 256
    tpp_main<<<nblocks, 64, 0, stream>>>(deltas, mask, w_ih, w_hh, b_ih, b_hh,
                                         w1, b1, w2, b2, partials);
    tpp_final<<<1, 256, 0, stream>>>(partials, nblocks, out);
}

// Round 8
// 503.894 us; speedup vs baseline: 1.4599x; 1.4599x over previous
//
#include <hip/hip_runtime.h>
#include <math.h>

// NeuralTPP: B=4096, L=512, H=HH=32 — MFMA + 4-wave gate-split.
// Block = 256 thr = 4 waves, 16 seqs/block, 256 blocks (1 block/CU).
// Wave role w = tid>>6: w0=r-gate, w1=z-gate, w2=n-gate + h-update,
// w3=intensity. Each wave: 2x mfma_f32_16x16x32_f16 (its gate's two
// 16-row tiles, R5-verified row permutation) on its own SIMD, then its
// quarter of the transcendental work. Exchange via LDS:
//   w0/w1 -> sigma(r),sigma(z) fp32 [16][36] (bank-spread, b128 rw)
//   w2    -> h as f16 B-fragment, natural k-order [16][40] (ds_*_b128)
//   w3    -> packed (raw,v2) into padded ibuf [16*520]
// Two barriers/step; w3's work overlaps w2's serial chain.
// Phase 2 (softplus/log over 16x512 items) on all 256 threads.

constexpr int Bn = 4096;
constexpr int Ln = 512;
constexpr float EPSf = 1e-8f;

typedef _Float16 f16x8 __attribute__((ext_vector_type(8)));
typedef float    f32x4 __attribute__((ext_vector_type(4)));

__device__ __forceinline__ float sigmoidf_(float x) {
    return __fdividef(1.0f, 1.0f + __expf(-x));
}
__device__ __forceinline__ float softplusf_(float x) {
    return fmaxf(x, 0.0f) + __logf(1.0f + __expf(-fabsf(x)));
}

union PK2 { _Float16 f[2]; unsigned u; };

__global__ __launch_bounds__(256, 1)
void tpp_main(const float* __restrict__ deltas,
              const float* __restrict__ mask,
              const float* __restrict__ w_ih,
              const float* __restrict__ w_hh,
              const float* __restrict__ b_ih,
              const float* __restrict__ b_hh,
              const float* __restrict__ w1,
              const float* __restrict__ b1,
              const float* __restrict__ w2,
              const float* __restrict__ b2,
              float* __restrict__ partials)   // [2 * gridDim.x]
{
    const int tid = threadIdx.x;
    const int w   = tid >> 6;            // wave role: 0=r 1=z 2=n 3=p
    const int l   = tid & 63;
    const int c   = l & 15;              // batch column / A row rr
    const int g   = l >> 4;              // k-group & C row-group
    const int b0  = blockIdx.x * 16;

    __shared__ __align__(16) _Float16 hbuf[16][40];   // h as f16, stride 80 B
    __shared__ __align__(16) float    rbuf[16][36];   // sigma(r), stride 144 B
    __shared__ __align__(16) float    zbuf[16][36];   // sigma(z)
    __shared__ unsigned ibuf[16 * 520];               // padded (raw,v2) packs

    // ---- A fragments for this wave's gate block G=w, tiles p=0,1 ----
    // tile row rr=c holds unit u = 8*(rr>>2) + 4p + (rr&3); k-cols j=8g+e.
    f16x8 Af[2];
    {
        const int ub = 8 * (c >> 2) + (c & 3);
        const int j0 = 8 * g;
#pragma unroll
        for (int p = 0; p < 2; ++p) {
            const int up = ub + 4 * p;
            const float* src =
                (w == 0) ? (w_hh + (size_t)up * 32 + j0) :
                (w == 1) ? (w_hh + (size_t)(32 + up) * 32 + j0) :
                (w == 2) ? (w_hh + (size_t)(64 + up) * 32 + j0) :
                           (w1   + (size_t)up * 33 + 1 + j0);
#pragma unroll
            for (int e = 0; e < 8; ++e) Af[p][e] = (_Float16)src[e];
        }
    }

    // ---- per-role scalars for this lane's 8 units u = 8g+e ----
    float cA[8], cB[8], cC[8], cD[8];
    float civs = 0.0f, b2v = 0.0f;
    if (w < 2) {
#pragma unroll
        for (int e = 0; e < 8; ++e) {
            const int u = 8 * g + e;
            cA[e] = w_ih[32 * w + u];
            cB[e] = b_ih[32 * w + u] + b_hh[32 * w + u];
        }
    } else if (w == 2) {
#pragma unroll
        for (int e = 0; e < 8; ++e) {
            const int u = 8 * g + e;
            cA[e] = w_ih[64 + u];          // wihn
            cB[e] = b_ih[64 + u];          // bin
            cC[e] = b_hh[64 + u];          // bhn
        }
    } else {
#pragma unroll
        for (int e = 0; e < 8; ++e) {
            const int u = 8 * g + e;
            cA[e] = w1[(size_t)u * 33];    // w1_tau
            cB[e] = b1[u];                 // b1
            cC[e] = w2[u];                 // w2
            cD[e] = cA[e] * cC[e];         // civ
            civs += cD[e];
        }
        b2v = b2[0];
    }

    const float* dp0 = deltas + (size_t)(b0 + c) * Ln;
    const float* mp0 = mask   + (size_t)(b0 + c) * Ln;

    float hreg[8];
#pragma unroll
    for (int e = 0; e < 8; ++e) hreg[e] = 0.0f;

    // init h buffer (w2's lanes cover all [c][0..31])
    if (w == 2) {
        f16x8 zz = {};
        *(f16x8*)&hbuf[c][8 * g] = zz;
    }
    __syncthreads();

    float tau = dp0[0];
    float m   = mp0[0];

    const f32x4 z4 = {0.0f, 0.0f, 0.0f, 0.0f};

    for (int t = 0; t < Ln; ++t) {
        const int tn = (t + 1 < Ln) ? (t + 1) : (Ln - 1);
        const float tau_n = dp0[tn];
        const float m_n   = mp0[tn];

        // ---- B fragment (h_{t-1}) + this wave's 2 MFMAs ----
        const f16x8 bf = *(const f16x8*)&hbuf[c][8 * g];
        f32x4 a0 = __builtin_amdgcn_mfma_f32_16x16x32_f16(Af[0], bf, z4, 0, 0, 0);
        f32x4 a1 = __builtin_amdgcn_mfma_f32_16x16x32_f16(Af[1], bf, z4, 0, 0, 0);

        float t0[8], t1[8];
        if (w < 2) {
            // sigma(gate) for 8 units, batched
            float pe[8], ex[8];
#pragma unroll
            for (int d = 0; d < 4; ++d) {
                pe[d]     = a0[d] + fmaf(tau, cA[d], cB[d]);
                pe[4 + d] = a1[d] + fmaf(tau, cA[4 + d], cB[4 + d]);
            }
#pragma unroll
            for (int e = 0; e < 8; ++e) ex[e] = __expf(-pe[e]);
            float* dst = (w == 0) ? &rbuf[c][8 * g] : &zbuf[c][8 * g];
            float4 s0, s1;
            s0.x = __frcp_rn(1.0f + ex[0]); s0.y = __frcp_rn(1.0f + ex[1]);
            s0.z = __frcp_rn(1.0f + ex[2]); s0.w = __frcp_rn(1.0f + ex[3]);
            s1.x = __frcp_rn(1.0f + ex[4]); s1.y = __frcp_rn(1.0f + ex[5]);
            s1.z = __frcp_rn(1.0f + ex[6]); s1.w = __frcp_rn(1.0f + ex[7]);
            *(float4*)dst       = s0;
            *(float4*)(dst + 4) = s1;
        } else if (w == 2) {
#pragma unroll
            for (int d = 0; d < 4; ++d) {
                t0[d]     = fmaf(tau, cA[d], cB[d]);          // n pre base
                t0[4 + d] = fmaf(tau, cA[4 + d], cB[4 + d]);
                t1[d]     = a0[d] + cC[d];                    // gn + bhn
                t1[4 + d] = a1[d] + cC[4 + d];
            }
        } else {
#pragma unroll
            for (int d = 0; d < 4; ++d) {
                t0[d]     = a0[d] + fmaf(tau, cA[d], cB[d]);  // intensity pre
                t0[4 + d] = a1[d] + fmaf(tau, cA[4 + d], cB[4 + d]);
            }
        }

        __syncthreads();                       // bar1: sigma(r), sigma(z) ready

        if (w == 2) {
            const float4 r0 = *(const float4*)&rbuf[c][8 * g];
            const float4 r1 = *(const float4*)&rbuf[c][8 * g + 4];
            const float4 zz0 = *(const float4*)&zbuf[c][8 * g];
            const float4 zz1 = *(const float4*)&zbuf[c][8 * g + 4];
            float npe[8], nex[8];
            npe[0] = t0[0] + r0.x * t1[0];  npe[1] = t0[1] + r0.y * t1[1];
            npe[2] = t0[2] + r0.z * t1[2];  npe[3] = t0[3] + r0.w * t1[3];
            npe[4] = t0[4] + r1.x * t1[4];  npe[5] = t0[5] + r1.y * t1[5];
            npe[6] = t0[6] + r1.z * t1[6];  npe[7] = t0[7] + r1.w * t1[7];
#pragma unroll
            for (int e = 0; e < 8; ++e)
                nex[e] = __expf(2.0f * fminf(npe[e], 15.0f));
            float zg[8];
            zg[0] = zz0.x; zg[1] = zz0.y; zg[2] = zz0.z; zg[3] = zz0.w;
            zg[4] = zz1.x; zg[5] = zz1.y; zg[6] = zz1.z; zg[7] = zz1.w;
            f16x8 hv;
#pragma unroll
            for (int e = 0; e < 8; ++e) {
                const float nn  = __fdividef(nex[e] - 1.0f, nex[e] + 1.0f);
                const float hn2 = fmaf(zg[e], hreg[e] - nn, nn);
                hreg[e] = fmaf(m, hn2 - hreg[e], hreg[e]);
                hv[e]   = (_Float16)hreg[e];
            }
            *(f16x8*)&hbuf[c][8 * g] = hv;
        } else if (w == 3) {
            float aex[8];
#pragma unroll
            for (int e = 0; e < 8; ++e)
                aex[e] = __expf(2.0f * fminf(t0[e], 15.0f));
            float v1p = 0.0f, v2p = civs;
#pragma unroll
            for (int e = 0; e < 8; ++e) {
                const float a = __fdividef(aex[e] - 1.0f, aex[e] + 1.0f);
                v1p = fmaf(a, cC[e], v1p);
                v2p = fmaf(a * a, -cD[e], v2p);
            }
            v1p += __shfl_xor(v1p, 16, 64);
            v1p += __shfl_xor(v1p, 32, 64);
            v2p += __shfl_xor(v2p, 16, 64);
            v2p += __shfl_xor(v2p, 32, 64);
            if (l < 16) {
                PK2 pk;
                pk.f[0] = (_Float16)(v1p + b2v);
                pk.f[1] = (_Float16)v2p;
                ibuf[l * 520 + t] = pk.u;
            }
        }

        __syncthreads();                       // bar2: h_t ready
        tau = tau_n;
        m   = m_n;
    }

    // ---- phase 2: LL transcendentals over 16 x 512 items, 256 threads ----
    float T = 0.0f, M = 0.0f;
#pragma unroll 4
    for (int it = 0; it < 32; ++it) {
        const int idx = it * 256 + tid;         // cc*512 + tt
        const int cc  = idx >> 9;
        const int tt  = idx & 511;
        PK2 pk; pk.u = ibuf[cc * 520 + tt];
        const float raw = (float)pk.f[0];
        const float v2  = (float)pk.f[1];
        const float mm  = mask[(size_t)(b0 + cc) * Ln + tt];
        const float phi  = softplusf_(raw);
        const float dphi = sigmoidf_(raw) * v2;
        const float lam  = softplusf_(dphi) + EPSf;
        T = fmaf(__logf(lam) - phi, mm, T);
        M += mm;
    }
#pragma unroll
    for (int d = 1; d < 64; d <<= 1) {
        T += __shfl_xor(T, d, 64);
        M += __shfl_xor(M, d, 64);
    }
    __shared__ float sT[4], sM[4];
    if (l == 0) { sT[w] = T; sM[w] = M; }
    __syncthreads();
    if (tid == 0) {
        partials[blockIdx.x]             = sT[0] + sT[1] + sT[2] + sT[3];
        partials[gridDim.x + blockIdx.x] = sM[0] + sM[1] + sM[2] + sM[3];
    }
}

__global__ __launch_bounds__(256)
void tpp_final(const float* __restrict__ partials, int nparts,
               float* __restrict__ out)
{
    const int tid = threadIdx.x;
    double T = 0.0, M = 0.0;
    for (int k = tid; k < nparts; k += 256) {
        T += (double)partials[k];
        M += (double)partials[nparts + k];
    }
#pragma unroll
    for (int d = 1; d < 64; d <<= 1) {
        T += __shfl_xor(T, d, 64);
        M += __shfl_xor(M, d, 64);
    }
    __shared__ double sT[4], sM[4];
    const int w = tid >> 6;
    if ((tid & 63) == 0) { sT[w] = T; sM[w] = M; }
    __syncthreads();
    if (tid == 0) {
        const double t2 = sT[0] + sT[1] + sT[2] + sT[3];
        const double m2 = sM[0] + sM[1] + sM[2] + sM[3];
        out[0] = (float)(t2 / (m2 + (double)EPSf));
    }
}

extern "C" void kernel_launch(void* const* d_in, const int* in_sizes, int n_in,
                              void* d_out, int out_size, void* d_ws, size_t ws_size,
                              hipStream_t stream) {
    const float* deltas = (const float*)d_in[0];
    const float* mask   = (const float*)d_in[1];
    const float* w_ih   = (const float*)d_in[2];
    const float* w_hh   = (const float*)d_in[3];
    const float* b_ih   = (const float*)d_in[4];
    const float* b_hh   = (const float*)d_in[5];
    const float* w1     = (const float*)d_in[6];
    const float* b1     = (const float*)d_in[7];
    const float* w2     = (const float*)d_in[8];
    const float* b2     = (const float*)d_in[9];
    float* out = (float*)d_out;
    float* partials = (float*)d_ws;      // 2 * 256 * 4 B

    const int nblocks = Bn / 16;         // 256
    tpp_main<<<nblocks, 256, 0, stream>>>(deltas, mask, w_ih, w_hh, b_ih, b_hh,
                                          w1, b1, w2, b2, partials);
    tpp_final<<<1, 256, 0, stream>>>(partials, nblocks, out);
}

// Round 9
// 456.229 us; speedup vs baseline: 1.6124x; 1.1045x over previous
//
#include <hip/hip_runtime.h>
#include <math.h>

// NeuralTPP: B=4096, L=512, H=HH=32 — MFMA + 4-wave gate-split + LDS inputs.
// Block = 256 thr = 4 waves, 16 seqs/block, 256 blocks (1 block/CU).
// Wave role w: 0=r-gate, 1=z-gate, 2=n-gate+h-update, 3=intensity.
// Each wave: 2x mfma_f32_16x16x32_f16 (R5-verified row permutation).
// KEY this round: (tau,mask) for all 16 seqs staged to LDS upfront ->
// ZERO VMEM inside the recurrence loop -> __syncthreads vmcnt(0) drains
// nothing (the per-step global-load latency no longer sits inside the
// barriers). Phase 2 reads mask from LDS too.

constexpr int Bn = 4096;
constexpr int Ln = 512;
constexpr float EPSf = 1e-8f;

typedef _Float16 f16x8 __attribute__((ext_vector_type(8)));
typedef float    f32x4 __attribute__((ext_vector_type(4)));

__device__ __forceinline__ float sigmoidf_(float x) {
    return __fdividef(1.0f, 1.0f + __expf(-x));
}
__device__ __forceinline__ float softplusf_(float x) {
    return fmaxf(x, 0.0f) + __logf(1.0f + __expf(-fabsf(x)));
}

union PK2 { _Float16 f[2]; unsigned u; };

__global__ __launch_bounds__(256, 1)
void tpp_main(const float* __restrict__ deltas,
              const float* __restrict__ mask,
              const float* __restrict__ w_ih,
              const float* __restrict__ w_hh,
              const float* __restrict__ b_ih,
              const float* __restrict__ b_hh,
              const float* __restrict__ w1,
              const float* __restrict__ b1,
              const float* __restrict__ w2,
              const float* __restrict__ b2,
              float* __restrict__ partials)   // [2 * gridDim.x]
{
    const int tid = threadIdx.x;
    const int w   = tid >> 6;            // wave role: 0=r 1=z 2=n 3=p
    const int l   = tid & 63;
    const int c   = l & 15;              // batch column / A row rr
    const int g   = l >> 4;              // k-group & C row-group
    const int b0  = blockIdx.x * 16;

    __shared__ __align__(16) _Float16 hbuf[16][40];   // h as f16 (80 B stride)
    __shared__ __align__(16) float    rbuf[16][36];   // sigma(r)
    __shared__ __align__(16) float    zbuf[16][36];   // sigma(z)
    __shared__ unsigned ibuf[16 * 520];               // packed (raw,v2)
    __shared__ float2   tm[16][514];                  // (tau, mask) staged

    // ---- stage (tau, mask) for the block's 16 sequences into LDS ----
    for (int q = tid; q < 16 * 128; q += 256) {       // 2048 float4 slots
        const int cc = q >> 7;
        const int t4 = (q & 127) << 2;
        const float4 dv = *(const float4*)(deltas + (size_t)(b0 + cc) * Ln + t4);
        const float4 mv = *(const float4*)(mask   + (size_t)(b0 + cc) * Ln + t4);
        tm[cc][t4 + 0] = make_float2(dv.x, mv.x);
        tm[cc][t4 + 1] = make_float2(dv.y, mv.y);
        tm[cc][t4 + 2] = make_float2(dv.z, mv.z);
        tm[cc][t4 + 3] = make_float2(dv.w, mv.w);
    }

    // ---- A fragments for this wave's gate block G=w, tiles p=0,1 ----
    f16x8 Af[2];
    {
        const int ub = 8 * (c >> 2) + (c & 3);
        const int j0 = 8 * g;
#pragma unroll
        for (int p = 0; p < 2; ++p) {
            const int up = ub + 4 * p;
            const float* src =
                (w == 0) ? (w_hh + (size_t)up * 32 + j0) :
                (w == 1) ? (w_hh + (size_t)(32 + up) * 32 + j0) :
                (w == 2) ? (w_hh + (size_t)(64 + up) * 32 + j0) :
                           (w1   + (size_t)up * 33 + 1 + j0);
#pragma unroll
            for (int e = 0; e < 8; ++e) Af[p][e] = (_Float16)src[e];
        }
    }

    // ---- per-role scalars for this lane's 8 units u = 8g+e ----
    float cA[8], cB[8], cC[8], cD[8];
    float civs = 0.0f, b2v = 0.0f;
    if (w < 2) {
#pragma unroll
        for (int e = 0; e < 8; ++e) {
            const int u = 8 * g + e;
            cA[e] = w_ih[32 * w + u];
            cB[e] = b_ih[32 * w + u] + b_hh[32 * w + u];
        }
    } else if (w == 2) {
#pragma unroll
        for (int e = 0; e < 8; ++e) {
            const int u = 8 * g + e;
            cA[e] = w_ih[64 + u];          // wihn
            cB[e] = b_ih[64 + u];          // bin
            cC[e] = b_hh[64 + u];          // bhn
        }
    } else {
#pragma unroll
        for (int e = 0; e < 8; ++e) {
            const int u = 8 * g + e;
            cA[e] = w1[(size_t)u * 33];    // w1_tau
            cB[e] = b1[u];                 // b1
            cC[e] = w2[u];                 // w2
            cD[e] = cA[e] * cC[e];         // civ
            civs += cD[e];
        }
        b2v = b2[0];
    }

    float hreg[8];
#pragma unroll
    for (int e = 0; e < 8; ++e) hreg[e] = 0.0f;

    if (w == 2) {                          // init h buffer
        f16x8 zz = {};
        *(f16x8*)&hbuf[c][8 * g] = zz;
    }
    __syncthreads();

    const f32x4 z4 = {0.0f, 0.0f, 0.0f, 0.0f};

    for (int t = 0; t < Ln; ++t) {
        const float2 tmv = tm[c][t];
        const float tau = tmv.x;
        const float m   = tmv.y;

        // ---- B fragment (h_{t-1}) + this wave's 2 MFMAs ----
        const f16x8 bf = *(const f16x8*)&hbuf[c][8 * g];
        f32x4 a0 = __builtin_amdgcn_mfma_f32_16x16x32_f16(Af[0], bf, z4, 0, 0, 0);
        f32x4 a1 = __builtin_amdgcn_mfma_f32_16x16x32_f16(Af[1], bf, z4, 0, 0, 0);

        float t0[8], t1[8];
        if (w < 2) {
            float pe[8], ex[8];
#pragma unroll
            for (int d = 0; d < 4; ++d) {
                pe[d]     = a0[d] + fmaf(tau, cA[d], cB[d]);
                pe[4 + d] = a1[d] + fmaf(tau, cA[4 + d], cB[4 + d]);
            }
#pragma unroll
            for (int e = 0; e < 8; ++e) ex[e] = __expf(-pe[e]);
            float* dst = (w == 0) ? &rbuf[c][8 * g] : &zbuf[c][8 * g];
            float4 s0, s1;
            s0.x = __frcp_rn(1.0f + ex[0]); s0.y = __frcp_rn(1.0f + ex[1]);
            s0.z = __frcp_rn(1.0f + ex[2]); s0.w = __frcp_rn(1.0f + ex[3]);
            s1.x = __frcp_rn(1.0f + ex[4]); s1.y = __frcp_rn(1.0f + ex[5]);
            s1.z = __frcp_rn(1.0f + ex[6]); s1.w = __frcp_rn(1.0f + ex[7]);
            *(float4*)dst       = s0;
            *(float4*)(dst + 4) = s1;
        } else if (w == 2) {
#pragma unroll
            for (int d = 0; d < 4; ++d) {
                t0[d]     = fmaf(tau, cA[d], cB[d]);          // n pre base
                t0[4 + d] = fmaf(tau, cA[4 + d], cB[4 + d]);
                t1[d]     = a0[d] + cC[d];                    // gn + bhn
                t1[4 + d] = a1[d] + cC[4 + d];
            }
        } else {
#pragma unroll
            for (int d = 0; d < 4; ++d) {
                t0[d]     = a0[d] + fmaf(tau, cA[d], cB[d]);  // intensity pre
                t0[4 + d] = a1[d] + fmaf(tau, cA[4 + d], cB[4 + d]);
            }
        }

        __syncthreads();                       // bar1: sigma(r), sigma(z) ready

        if (w == 2) {
            const float4 r0 = *(const float4*)&rbuf[c][8 * g];
            const float4 r1 = *(const float4*)&rbuf[c][8 * g + 4];
            const float4 zz0 = *(const float4*)&zbuf[c][8 * g];
            const float4 zz1 = *(const float4*)&zbuf[c][8 * g + 4];
            float npe[8], nex[8];
            npe[0] = t0[0] + r0.x * t1[0];  npe[1] = t0[1] + r0.y * t1[1];
            npe[2] = t0[2] + r0.z * t1[2];  npe[3] = t0[3] + r0.w * t1[3];
            npe[4] = t0[4] + r1.x * t1[4];  npe[5] = t0[5] + r1.y * t1[5];
            npe[6] = t0[6] + r1.z * t1[6];  npe[7] = t0[7] + r1.w * t1[7];
#pragma unroll
            for (int e = 0; e < 8; ++e)
                nex[e] = __expf(2.0f * fminf(npe[e], 15.0f));
            float zg[8];
            zg[0] = zz0.x; zg[1] = zz0.y; zg[2] = zz0.z; zg[3] = zz0.w;
            zg[4] = zz1.x; zg[5] = zz1.y; zg[6] = zz1.z; zg[7] = zz1.w;
            f16x8 hv;
#pragma unroll
            for (int e = 0; e < 8; ++e) {
                const float nn  = __fdividef(nex[e] - 1.0f, nex[e] + 1.0f);
                const float hn2 = fmaf(zg[e], hreg[e] - nn, nn);
                hreg[e] = fmaf(m, hn2 - hreg[e], hreg[e]);
                hv[e]   = (_Float16)hreg[e];
            }
            *(f16x8*)&hbuf[c][8 * g] = hv;
        } else if (w == 3) {
            float aex[8];
#pragma unroll
            for (int e = 0; e < 8; ++e)
                aex[e] = __expf(2.0f * fminf(t0[e], 15.0f));
            float v1p = 0.0f, v2p = civs;
#pragma unroll
            for (int e = 0; e < 8; ++e) {
                const float a = __fdividef(aex[e] - 1.0f, aex[e] + 1.0f);
                v1p = fmaf(a, cC[e], v1p);
                v2p = fmaf(a * a, -cD[e], v2p);
            }
            v1p += __shfl_xor(v1p, 16, 64);
            v1p += __shfl_xor(v1p, 32, 64);
            v2p += __shfl_xor(v2p, 16, 64);
            v2p += __shfl_xor(v2p, 32, 64);
            if (l < 16) {
                PK2 pk;
                pk.f[0] = (_Float16)(v1p + b2v);
                pk.f[1] = (_Float16)v2p;
                ibuf[l * 520 + t] = pk.u;
            }
        }

        __syncthreads();                       // bar2: h_t ready
    }

    // ---- phase 2: LL transcendentals over 16 x 512 items, 256 threads ----
    float T = 0.0f, M = 0.0f;
#pragma unroll 4
    for (int it = 0; it < 32; ++it) {
        const int idx = it * 256 + tid;         // cc*512 + tt
        const int cc  = idx >> 9;
        const int tt  = idx & 511;
        PK2 pk; pk.u = ibuf[cc * 520 + tt];
        const float raw = (float)pk.f[0];
        const float v2  = (float)pk.f[1];
        const float mm  = tm[cc][tt].y;
        const float phi  = softplusf_(raw);
        const float dphi = sigmoidf_(raw) * v2;
        const float lam  = softplusf_(dphi) + EPSf;
        T = fmaf(__logf(lam) - phi, mm, T);
        M += mm;
    }
#pragma unroll
    for (int d = 1; d < 64; d <<= 1) {
        T += __shfl_xor(T, d, 64);
        M += __shfl_xor(M, d, 64);
    }
    __shared__ float sT[4], sM[4];
    if (l == 0) { sT[w] = T; sM[w] = M; }
    __syncthreads();
    if (tid == 0) {
        partials[blockIdx.x]             = sT[0] + sT[1] + sT[2] + sT[3];
        partials[gridDim.x + blockIdx.x] = sM[0] + sM[1] + sM[2] + sM[3];
    }
}

__global__ __launch_bounds__(256)
void tpp_final(const float* __restrict__ partials, int nparts,
               float* __restrict__ out)
{
    const int tid = threadIdx.x;
    double T = 0.0, M = 0.0;
    for (int k = tid; k < nparts; k += 256) {
        T += (double)partials[k];
        M += (double)partials[nparts + k];
    }
#pragma unroll
    for (int d = 1; d < 64; d <<= 1) {
        T += __shfl_xor(T, d, 64);
        M += __shfl_xor(M, d, 64);
    }
    __shared__ double sT[4], sM[4];
    const int w = tid >> 6;
    if ((tid & 63) == 0) { sT[w] = T; sM[w] = M; }
    __syncthreads();
    if (tid == 0) {
        const double t2 = sT[0] + sT[1] + sT[2] + sT[3];
        const double m2 = sM[0] + sM[1] + sM[2] + sM[3];
        out[0] = (float)(t2 / (m2 + (double)EPSf));
    }
}

extern "C" void kernel_launch(void* const* d_in, const int* in_sizes, int n_in,
                              void* d_out, int out_size, void* d_ws, size_t ws_size,
                              hipStream_t stream) {
    const float* deltas = (const float*)d_in[0];
    const float* mask   = (const float*)d_in[1];
    const float* w_ih   = (const float*)d_in[2];
    const float* w_hh   = (const float*)d_in[3];
    const float* b_ih   = (const float*)d_in[4];
    const float* b_hh   = (const float*)d_in[5];
    const float* w1     = (const float*)d_in[6];
    const float* b1     = (const float*)d_in[7];
    const float* w2     = (const float*)d_in[8];
    const float* b2     = (const float*)d_in[9];
    float* out = (float*)d_out;
    float* partials = (float*)d_ws;      // 2 * 256 * 4 B

    const int nblocks = Bn / 16;         // 256
    tpp_main<<<nblocks, 256, 0, stream>>>(deltas, mask, w_ih, w_hh, b_ih, b_hh,
                                          w1, b1, w2, b2, partials);
    tpp_final<<<1, 256, 0, stream>>>(partials, nblocks, out);
}

// Round 10
// 454.741 us; speedup vs baseline: 1.6177x; 1.0033x over previous
//
#include <hip/hip_runtime.h>
#include <math.h>

// NeuralTPP: B=4096, L=512, H=HH=32 — MFMA + 4-wave gate-split + LDS inputs.
// Block = 256 thr = 4 waves, 16 seqs/block, 256 blocks (1 block/CU).
// Wave role w: 0=r-gate, 1=z-gate, 2=n-gate+h-update, 3=intensity.
// R9 lever: amdgpu_waves_per_eu(1,1) — tell the backend the TRUE occupancy
// (1 wave/EU) so the register allocator stops squeezing to 56-130 VGPRs and
// the scheduler emits the 8-wide transcendental levels interleaved (ILP)
// instead of unit-serial chains. Everything else identical to R8.

constexpr int Bn = 4096;
constexpr int Ln = 512;
constexpr float EPSf = 1e-8f;

typedef _Float16 f16x8 __attribute__((ext_vector_type(8)));
typedef float    f32x4 __attribute__((ext_vector_type(4)));

__device__ __forceinline__ float sigmoidf_(float x) {
    return __fdividef(1.0f, 1.0f + __expf(-x));
}
__device__ __forceinline__ float softplusf_(float x) {
    return fmaxf(x, 0.0f) + __logf(1.0f + __expf(-fabsf(x)));
}

union PK2 { _Float16 f[2]; unsigned u; };

__global__ __launch_bounds__(256)
__attribute__((amdgpu_waves_per_eu(1, 1)))
void tpp_main(const float* __restrict__ deltas,
              const float* __restrict__ mask,
              const float* __restrict__ w_ih,
              const float* __restrict__ w_hh,
              const float* __restrict__ b_ih,
              const float* __restrict__ b_hh,
              const float* __restrict__ w1,
              const float* __restrict__ b1,
              const float* __restrict__ w2,
              const float* __restrict__ b2,
              float* __restrict__ partials)   // [2 * gridDim.x]
{
    const int tid = threadIdx.x;
    const int w   = tid >> 6;            // wave role: 0=r 1=z 2=n 3=p
    const int l   = tid & 63;
    const int c   = l & 15;              // batch column / A row rr
    const int g   = l >> 4;              // k-group & C row-group
    const int b0  = blockIdx.x * 16;

    __shared__ __align__(16) _Float16 hbuf[16][40];   // h as f16 (80 B stride)
    __shared__ __align__(16) float    rbuf[16][36];   // sigma(r)
    __shared__ __align__(16) float    zbuf[16][36];   // sigma(z)
    __shared__ unsigned ibuf[16 * 520];               // packed (raw,v2)
    __shared__ float2   tm[16][514];                  // (tau, mask) staged

    // ---- stage (tau, mask) for the block's 16 sequences into LDS ----
    for (int q = tid; q < 16 * 128; q += 256) {       // 2048 float4 slots
        const int cc = q >> 7;
        const int t4 = (q & 127) << 2;
        const float4 dv = *(const float4*)(deltas + (size_t)(b0 + cc) * Ln + t4);
        const float4 mv = *(const float4*)(mask   + (size_t)(b0 + cc) * Ln + t4);
        tm[cc][t4 + 0] = make_float2(dv.x, mv.x);
        tm[cc][t4 + 1] = make_float2(dv.y, mv.y);
        tm[cc][t4 + 2] = make_float2(dv.z, mv.z);
        tm[cc][t4 + 3] = make_float2(dv.w, mv.w);
    }

    // ---- A fragments for this wave's gate block G=w, tiles p=0,1 ----
    f16x8 Af[2];
    {
        const int ub = 8 * (c >> 2) + (c & 3);
        const int j0 = 8 * g;
#pragma unroll
        for (int p = 0; p < 2; ++p) {
            const int up = ub + 4 * p;
            const float* src =
                (w == 0) ? (w_hh + (size_t)up * 32 + j0) :
                (w == 1) ? (w_hh + (size_t)(32 + up) * 32 + j0) :
                (w == 2) ? (w_hh + (size_t)(64 + up) * 32 + j0) :
                           (w1   + (size_t)up * 33 + 1 + j0);
#pragma unroll
            for (int e = 0; e < 8; ++e) Af[p][e] = (_Float16)src[e];
        }
    }

    // ---- per-role scalars for this lane's 8 units u = 8g+e ----
    float cA[8], cB[8], cC[8], cD[8];
    float civs = 0.0f, b2v = 0.0f;
    if (w < 2) {
#pragma unroll
        for (int e = 0; e < 8; ++e) {
            const int u = 8 * g + e;
            cA[e] = w_ih[32 * w + u];
            cB[e] = b_ih[32 * w + u] + b_hh[32 * w + u];
        }
    } else if (w == 2) {
#pragma unroll
        for (int e = 0; e < 8; ++e) {
            const int u = 8 * g + e;
            cA[e] = w_ih[64 + u];          // wihn
            cB[e] = b_ih[64 + u];          // bin
            cC[e] = b_hh[64 + u];          // bhn
        }
    } else {
#pragma unroll
        for (int e = 0; e < 8; ++e) {
            const int u = 8 * g + e;
            cA[e] = w1[(size_t)u * 33];    // w1_tau
            cB[e] = b1[u];                 // b1
            cC[e] = w2[u];                 // w2
            cD[e] = cA[e] * cC[e];         // civ
            civs += cD[e];
        }
        b2v = b2[0];
    }

    float hreg[8];
#pragma unroll
    for (int e = 0; e < 8; ++e) hreg[e] = 0.0f;

    if (w == 2) {                          // init h buffer
        f16x8 zz = {};
        *(f16x8*)&hbuf[c][8 * g] = zz;
    }
    __syncthreads();

    const f32x4 z4 = {0.0f, 0.0f, 0.0f, 0.0f};

    for (int t = 0; t < Ln; ++t) {
        const float2 tmv = tm[c][t];
        const float tau = tmv.x;
        const float m   = tmv.y;

        // ---- B fragment (h_{t-1}) + this wave's 2 MFMAs ----
        const f16x8 bf = *(const f16x8*)&hbuf[c][8 * g];
        f32x4 a0 = __builtin_amdgcn_mfma_f32_16x16x32_f16(Af[0], bf, z4, 0, 0, 0);
        f32x4 a1 = __builtin_amdgcn_mfma_f32_16x16x32_f16(Af[1], bf, z4, 0, 0, 0);

        float t0[8], t1[8];
        if (w < 2) {
            float pe[8], ex[8];
#pragma unroll
            for (int d = 0; d < 4; ++d) {
                pe[d]     = a0[d] + fmaf(tau, cA[d], cB[d]);
                pe[4 + d] = a1[d] + fmaf(tau, cA[4 + d], cB[4 + d]);
            }
#pragma unroll
            for (int e = 0; e < 8; ++e) ex[e] = __expf(-pe[e]);
            float* dst = (w == 0) ? &rbuf[c][8 * g] : &zbuf[c][8 * g];
            float4 s0, s1;
            s0.x = __frcp_rn(1.0f + ex[0]); s0.y = __frcp_rn(1.0f + ex[1]);
            s0.z = __frcp_rn(1.0f + ex[2]); s0.w = __frcp_rn(1.0f + ex[3]);
            s1.x = __frcp_rn(1.0f + ex[4]); s1.y = __frcp_rn(1.0f + ex[5]);
            s1.z = __frcp_rn(1.0f + ex[6]); s1.w = __frcp_rn(1.0f + ex[7]);
            *(float4*)dst       = s0;
            *(float4*)(dst + 4) = s1;
        } else if (w == 2) {
#pragma unroll
            for (int d = 0; d < 4; ++d) {
                t0[d]     = fmaf(tau, cA[d], cB[d]);          // n pre base
                t0[4 + d] = fmaf(tau, cA[4 + d], cB[4 + d]);
                t1[d]     = a0[d] + cC[d];                    // gn + bhn
                t1[4 + d] = a1[d] + cC[4 + d];
            }
        } else {
#pragma unroll
            for (int d = 0; d < 4; ++d) {
                t0[d]     = a0[d] + fmaf(tau, cA[d], cB[d]);  // intensity pre
                t0[4 + d] = a1[d] + fmaf(tau, cA[4 + d], cB[4 + d]);
            }
        }

        __syncthreads();                       // bar1: sigma(r), sigma(z) ready

        if (w == 2) {
            const float4 r0 = *(const float4*)&rbuf[c][8 * g];
            const float4 r1 = *(const float4*)&rbuf[c][8 * g + 4];
            const float4 zz0 = *(const float4*)&zbuf[c][8 * g];
            const float4 zz1 = *(const float4*)&zbuf[c][8 * g + 4];
            float npe[8], nex[8];
            npe[0] = t0[0] + r0.x * t1[0];  npe[1] = t0[1] + r0.y * t1[1];
            npe[2] = t0[2] + r0.z * t1[2];  npe[3] = t0[3] + r0.w * t1[3];
            npe[4] = t0[4] + r1.x * t1[4];  npe[5] = t0[5] + r1.y * t1[5];
            npe[6] = t0[6] + r1.z * t1[6];  npe[7] = t0[7] + r1.w * t1[7];
#pragma unroll
            for (int e = 0; e < 8; ++e)
                nex[e] = __expf(2.0f * fminf(npe[e], 15.0f));
            float zg[8];
            zg[0] = zz0.x; zg[1] = zz0.y; zg[2] = zz0.z; zg[3] = zz0.w;
            zg[4] = zz1.x; zg[5] = zz1.y; zg[6] = zz1.z; zg[7] = zz1.w;
            f16x8 hv;
#pragma unroll
            for (int e = 0; e < 8; ++e) {
                const float nn  = __fdividef(nex[e] - 1.0f, nex[e] + 1.0f);
                const float hn2 = fmaf(zg[e], hreg[e] - nn, nn);
                hreg[e] = fmaf(m, hn2 - hreg[e], hreg[e]);
                hv[e]   = (_Float16)hreg[e];
            }
            *(f16x8*)&hbuf[c][8 * g] = hv;
        } else if (w == 3) {
            float aex[8];
#pragma unroll
            for (int e = 0; e < 8; ++e)
                aex[e] = __expf(2.0f * fminf(t0[e], 15.0f));
            float v1p = 0.0f, v2p = civs;
#pragma unroll
            for (int e = 0; e < 8; ++e) {
                const float a = __fdividef(aex[e] - 1.0f, aex[e] + 1.0f);
                v1p = fmaf(a, cC[e], v1p);
                v2p = fmaf(a * a, -cD[e], v2p);
            }
            v1p += __shfl_xor(v1p, 16, 64);
            v1p += __shfl_xor(v1p, 32, 64);
            v2p += __shfl_xor(v2p, 16, 64);
            v2p += __shfl_xor(v2p, 32, 64);
            if (l < 16) {
                PK2 pk;
                pk.f[0] = (_Float16)(v1p + b2v);
                pk.f[1] = (_Float16)v2p;
                ibuf[l * 520 + t] = pk.u;
            }
        }

        __syncthreads();                       // bar2: h_t ready
    }

    // ---- phase 2: LL transcendentals over 16 x 512 items, 256 threads ----
    float T = 0.0f, M = 0.0f;
#pragma unroll 4
    for (int it = 0; it < 32; ++it) {
        const int idx = it * 256 + tid;         // cc*512 + tt
        const int cc  = idx >> 9;
        const int tt  = idx & 511;
        PK2 pk; pk.u = ibuf[cc * 520 + tt];
        const float raw = (float)pk.f[0];
        const float v2  = (float)pk.f[1];
        const float mm  = tm[cc][tt].y;
        const float phi  = softplusf_(raw);
        const float dphi = sigmoidf_(raw) * v2;
        const float lam  = softplusf_(dphi) + EPSf;
        T = fmaf(__logf(lam) - phi, mm, T);
        M += mm;
    }
#pragma unroll
    for (int d = 1; d < 64; d <<= 1) {
        T += __shfl_xor(T, d, 64);
        M += __shfl_xor(M, d, 64);
    }
    __shared__ float sT[4], sM[4];
    if (l == 0) { sT[w] = T; sM[w] = M; }
    __syncthreads();
    if (tid == 0) {
        partials[blockIdx.x]             = sT[0] + sT[1] + sT[2] + sT[3];
        partials[gridDim.x + blockIdx.x] = sM[0] + sM[1] + sM[2] + sM[3];
    }
}

__global__ __launch_bounds__(256)
void tpp_final(const float* __restrict__ partials, int nparts,
               float* __restrict__ out)
{
    const int tid = threadIdx.x;
    double T = 0.0, M = 0.0;
    for (int k = tid; k < nparts; k += 256) {
        T += (double)partials[k];
        M += (double)partials[nparts + k];
    }
#pragma unroll
    for (int d = 1; d < 64; d <<= 1) {
        T += __shfl_xor(T, d, 64);
        M += __shfl_xor(M, d, 64);
    }
    __shared__ double sT[4], sM[4];
    const int w = tid >> 6;
    if ((tid & 63) == 0) { sT[w] = T; sM[w] = M; }
    __syncthreads();
    if (tid == 0) {
        const double t2 = sT[0] + sT[1] + sT[2] + sT[3];
        const double m2 = sM[0] + sM[1] + sM[2] + sM[3];
        out[0] = (float)(t2 / (m2 + (double)EPSf));
    }
}

extern "C" void kernel_launch(void* const* d_in, const int* in_sizes, int n_in,
                              void* d_out, int out_size, void* d_ws, size_t ws_size,
                              hipStream_t stream) {
    const float* deltas = (const float*)d_in[0];
    const float* mask   = (const float*)d_in[1];
    const float* w_ih   = (const float*)d_in[2];
    const float* w_hh   = (const float*)d_in[3];
    const float* b_ih   = (const float*)d_in[4];
    const float* b_hh   = (const float*)d_in[5];
    const float* w1     = (const float*)d_in[6];
    const float* b1     = (const float*)d_in[7];
    const float* w2     = (const float*)d_in[8];
    const float* b2     = (const float*)d_in[9];
    float* out = (float*)d_out;
    float* partials = (float*)d_ws;      // 2 * 256 * 4 B

    const int nblocks = Bn / 16;         // 256
    tpp_main<<<nblocks, 256, 0, stream>>>(deltas, mask, w_ih, w_hh, b_ih, b_hh,
                                          w1, b1, w2, b2, partials);
    tpp_final<<<1, 256, 0, stream>>>(partials, nblocks, out);
}